// Round 13
// baseline (189.493 us; speedup 1.0000x reference)
//
#include <hip/hip_runtime.h>
#include <math.h>

#define KNN    10
#define NPTS   8192
#define HID    64
#define NF     76
#define Q      16                // queries per wave
#define CAP    64                // pass-2 collection capacity per query
#define F32_INF __uint_as_float(0x7F800000u)

__device__ __forceinline__ float rl(float v, int lane) {
    return __int_as_float(__builtin_amdgcn_readlane(__float_as_int(v), lane));
}

// ---------------------------------------------------------------------------
// Prep: pts4[i] = (x, y, z, x^2+y^2+z^2)  (w chain identical to all rounds).
// ---------------------------------------------------------------------------
__global__ __launch_bounds__(256) void prep_kernel(const float* __restrict__ cloud,
                                                   float4* __restrict__ pts4) {
    const int i = blockIdx.x * 256 + threadIdx.x;      // 0..32767
    const float x = cloud[i * 3 + 0];
    const float y = cloud[i * 3 + 1];
    const float z = cloud[i * 3 + 2];
    pts4[i] = make_float4(x, y, z, fmaf(z, z, fmaf(y, y, x * x)));
}

// ---------------------------------------------------------------------------
// KNN (unchanged from R12 — validated: absmax 4.39e-3 across 8 passes).
// Transposed scan, folded -2 coords, rank-11 chunk-minima threshold,
// exact R1-R11 key rebuild in rare hit branch, top-11 + self-filter.
// ---------------------------------------------------------------------------
__global__ __launch_bounds__(1024) void knn_kernel(const float4* __restrict__ pts4,
                                                   unsigned short* __restrict__ knn_idx) {
    __shared__ unsigned long long coll[CAP][65];   // [slot][block query+pad], 33 KB
    __shared__ float pk[16][Q][17];                // chunk minima, 17.4 KB
    __shared__ float tau_s[64];
    __shared__ int   cnt[64];

    const int t    = threadIdx.x;
    const int w    = t >> 6;                  // wave 0..15
    const int lane = t & 63;
    const int g    = w >> 2;                  // query group 0..3
    const int h    = w & 3;                   // candidate quarter 0..3
    const int bx   = blockIdx.x;              // 0..511
    const int b    = bx >> 7;                 // batch
    const int n_base = (bx & 127) * 64 + g * Q;   // batch-local first query of group
    const int lq_base = g * Q;                // block-local query base
    const int cb0 = h * (NPTS / 4);           // candidate base for this wave

    const float4* pb = pts4 + b * NPTS;

    if (t < 64) cnt[t] = 0;                   // visible after barrier 1

    float qxs[Q], qys[Q], qzs[Q], qss[Q];
#pragma unroll
    for (int qq = 0; qq < Q; ++qq) {
        const float4 qv = pb[n_base + qq];
        qxs[qq] = qv.x; qys[qq] = qv.y; qzs[qq] = qv.z; qss[qq] = qv.w;
    }

    // ---------------- pass 1: per-lane minima over this quarter ----------------
    float vmin[Q];
#pragma unroll
    for (int qq = 0; qq < Q; ++qq) vmin[qq] = F32_INF;

    float4 cp = pb[cb0 + lane];               // coalesced vector load
    for (int ti = 0; ti < NPTS / 4 / 64; ++ti) {  // 32 tiles
        const float4 np = (ti < NPTS / 4 / 64 - 1) ? pb[cb0 + (ti + 1) * 64 + lane] : cp;
        const float a2x = -2.0f * cp.x;       // once per tile, amortized /16
        const float a2y = -2.0f * cp.y;
        const float a2z = -2.0f * cp.z;
        const float aw  = cp.w;
#pragma unroll
        for (int qq = 0; qq < Q; ++qq) {
            const float v = fmaf(a2x, qxs[qq], fmaf(a2y, qys[qq], fmaf(a2z, qzs[qq], aw)));
            vmin[qq] = fminf(vmin[qq], v);    // self included (rank arg handles it)
        }
        cp = np;
    }

#pragma unroll
    for (int qq = 0; qq < Q; ++qq) {
        float v = vmin[qq];
        v = fminf(v, __shfl_xor(v, 32, 64));
        v = fminf(v, __shfl_xor(v, 16, 64));
        if (lane < 16) pk[w][qq][lane] = v;
    }
    __syncthreads();                          // barrier 1: pk + cnt visible

    if (h == 0) {
        float md[KNN + 1];
#pragma unroll
        for (int s = 0; s <= KNN; ++s) md[s] = F32_INF;
        const int qsel = lane & 15;           // 4-way replicated
#pragma unroll
        for (int cc = 0; cc < 64; ++cc) {
            float d = pk[g * 4 + (cc >> 4)][qsel][cc & 15];
#pragma unroll
            for (int u = 0; u <= KNN; ++u) {
                const float lo = fminf(md[u], d);
                d = fmaxf(md[u], d);
                md[u] = lo;
            }
        }
        if (lane < 16) tau_s[lq_base + lane] = md[KNN] + 1e-3f;
    }
    __syncthreads();                          // barrier 2: tau visible

    float taum[Q];
    {
        const float tv = tau_s[lq_base + (lane & 15)];
#pragma unroll
        for (int qq = 0; qq < Q; ++qq) taum[qq] = rl(tv, qq);   // -> SGPRs
    }

    // ---------------- pass 2: collect hits incl. self (rare) ----------------
    float4 cp2 = pb[cb0 + lane];
    int jcur = cb0 + lane;
    for (int ti = 0; ti < NPTS / 4 / 64; ++ti) {
        const float4 np = (ti < NPTS / 4 / 64 - 1) ? pb[cb0 + (ti + 1) * 64 + lane] : cp2;
        const float a2x = -2.0f * cp2.x;
        const float a2y = -2.0f * cp2.y;
        const float a2z = -2.0f * cp2.z;
        const float aw  = cp2.w;
#pragma unroll
        for (int qq = 0; qq < Q; ++qq) {
            const float v = fmaf(a2x, qxs[qq], fmaf(a2y, qys[qq], fmaf(a2z, qzs[qq], aw)));
            if (__builtin_expect(v <= taum[qq], 0)) {
                const float px = -0.5f * a2x;
                const float py = -0.5f * a2y;
                const float pz = -0.5f * a2z;
                const float dot = fmaf(pz, qzs[qq], fmaf(py, qys[qq], px * qxs[qq]));
                const float d2 = fmaf(-2.0f, dot, qss[qq] + aw);
                const unsigned int fb = __float_as_uint(d2);
                const unsigned int m =
                    fb ^ ((unsigned int)((int)fb >> 31) | 0x80000000u);  // monotone
                const unsigned long long key =
                    ((unsigned long long)m << 13) | (unsigned long long)(unsigned)jcur;
                const int slot = atomicAdd(&cnt[lq_base + qq], 1);
                if (slot < CAP) coll[slot][lq_base + qq] = key;
            }
        }
        cp2 = np; jcur += 64;
    }
    __syncthreads();

    // ---------------- phase 3: top-11 bubble, filter self by index ----------
    if (t < 64) {
        const int m = cnt[t];
        int mc = m;
#pragma unroll
        for (int off = 1; off < 64; off <<= 1)
            mc = max(mc, __shfl_xor(mc, off, 64));
        mc = __builtin_amdgcn_readfirstlane(mc);

        const int n = (bx & 127) * 64 + t;

        unsigned long long md[KNN + 1];
#pragma unroll
        for (int s = 0; s <= KNN; ++s) md[s] = ~0ULL;

        if (mc <= CAP) {
            for (int cc = 0; cc < mc; ++cc) {
                unsigned long long key = (cc < m) ? coll[cc][t] : ~0ULL;
#pragma unroll
                for (int u = 0; u <= KNN; ++u) {
                    const bool lt = key < md[u];
                    const unsigned long long lo = lt ? key : md[u];
                    key = lt ? md[u] : key;
                    md[u] = lo;
                }
            }
        } else {
            const float4 qv = pb[n];
            for (int j = 0; j < NPTS; ++j) {
                const float4 p = pb[j];
                const float dot = fmaf(p.z, qv.z, fmaf(p.y, qv.y, p.x * qv.x));
                const float d2 = fmaf(-2.0f, dot, qv.w + p.w);
                const unsigned int fb = __float_as_uint(d2);
                const unsigned int mm =
                    fb ^ ((unsigned int)((int)fb >> 31) | 0x80000000u);
                unsigned long long key =
                    ((unsigned long long)mm << 13) | (unsigned long long)j;
                key = (j == n) ? ~0ULL : key;
#pragma unroll
                for (int u = 0; u <= KNN; ++u) {
                    const bool lt = key < md[u];
                    const unsigned long long lo = lt ? key : md[u];
                    key = lt ? md[u] : key;
                    md[u] = lo;
                }
            }
        }

        unsigned short* outp = knn_idx + ((size_t)b * NPTS + n) * KNN;
        int outc = 0;
#pragma unroll
        for (int u = 0; u <= KNN; ++u) {
            const int idx = (int)(md[u] & 8191u);
            if (outc < KNN && idx != n) outp[outc++] = (unsigned short)idx;
        }
    }
}

// ---------------------------------------------------------------------------
// Features + MLP, 16 threads/point (R12 post-mortem: was ~45us latency-bound
// at 2 waves/SIMD with a serialized 1-lane feature build).
// Block = 512 thr = 8 waves = 32 points; grid 1024 -> 8192 waves, LDS
// 31.7 KB/block -> 4 blocks/CU = 32 waves/CU.
// Layout: lane = p*16 + s, s = subh*4 + subf; subh: 16 hidden units,
// subf: 19 features. Feature build parallel: lanes s<10 gather neighbor s
// and write its nbr/rel/dist features; mean/cov via 16-lane butterfly sums
// (lanes >=10 contribute 0); eigen computed by all lanes (same wave time).
// Layer 1: 19x16 fma/thread; combine over subf (shfl_xor 1,2); layer 2
// split 4-way over j per subh; final 16-lane butterfly; lane s==0 writes.
// ---------------------------------------------------------------------------
__global__ __launch_bounds__(512) void feat_mlp_kernel(const float4* __restrict__ pts4,
                                                       const float* __restrict__ W1,
                                                       const float* __restrict__ b1,
                                                       const float* __restrict__ W2,
                                                       const float* __restrict__ b2,
                                                       const unsigned short* __restrict__ knn_idx,
                                                       float* __restrict__ out) {
    __shared__ float w1s[NF * 68];            // padded stride, 20.7 KB
    __shared__ float b1s[HID];
    __shared__ float w2s[HID * 3];
    __shared__ float b2s[3];
    __shared__ float fs[32][NF + 2];          // stride 78, 10 KB

    const int t = threadIdx.x;
    for (int idx = t; idx < NF * HID; idx += 512)
        w1s[(idx >> 6) * 68 + (idx & 63)] = W1[idx];
    if (t < HID) b1s[t] = b1[t];
    if (t < HID * 3) w2s[t] = W2[t];
    if (t < 3) b2s[t] = b2[t];

    const int pl   = t >> 4;                  // point slot 0..31
    const int s    = t & 15;                  // sub-lane within point group
    const int subh = s >> 2;                  // hidden quarter
    const int subf = s & 3;                   // feature quarter
    const int gid = blockIdx.x * 32 + pl;     // 0..32767
    const int b = gid >> 13;
    const int n = gid & (NPTS - 1);
    const float4* pb = pts4 + b * NPTS;

    const float4 cq = pb[n];                  // same addr across group (broadcast)
    const float cx = cq.x, cy = cq.y, cz = cq.z;

    // gather: lanes s<10 load neighbor s and write its features
    float nxv = 0.f, nyv = 0.f, nzv = 0.f;
    if (s < KNN) {
        const int j = knn_idx[(size_t)gid * KNN + s];
        const float4 p = pb[j];
        nxv = p.x; nyv = p.y; nzv = p.z;
    }

    float* fr = fs[pl];
    if (s < KNN) {
        fr[3 + 3 * s + 0] = nxv;
        fr[3 + 3 * s + 1] = nyv;
        fr[3 + 3 * s + 2] = nzv;
        const float rx = nxv - cx, ry = nyv - cy, rz = nzv - cz;
        fr[33 + 3 * s + 0] = rx;
        fr[33 + 3 * s + 1] = ry;
        fr[33 + 3 * s + 2] = rz;
        fr[63 + s] = sqrtf(fmaf(rz, rz, fmaf(ry, ry, rx * rx)));
    }
    if (s == 10) { fr[0] = cx; fr[1] = cy; fr[2] = cz; }

    // 16-lane butterfly sums (xor offsets 1,2,4,8 stay within the group)
#define GSUM(v) { v += __shfl_xor(v, 1, 64); v += __shfl_xor(v, 2, 64); \
                  v += __shfl_xor(v, 4, 64); v += __shfl_xor(v, 8, 64); }
    float smx = nxv, smy = nyv, smz = nzv;
    GSUM(smx); GSUM(smy); GSUM(smz);
    const float mx = smx * 0.1f, my = smy * 0.1f, mz = smz * 0.1f;
    const float ex = (s < KNN) ? nxv - mx : 0.f;
    const float ey = (s < KNN) ? nyv - my : 0.f;
    const float ez = (s < KNN) ? nzv - mz : 0.f;
    float c00 = ex * ex, c01 = ex * ey, c02 = ex * ez;
    float c11 = ey * ey, c12 = ey * ez, c22 = ez * ez;
    GSUM(c00); GSUM(c01); GSUM(c02); GSUM(c11); GSUM(c12); GSUM(c22);
#undef GSUM
    const float sc = 1.0f / (KNN - 1);
    c00 *= sc; c01 *= sc; c02 *= sc; c11 *= sc; c12 *= sc; c22 *= sc;

    // fp32 closed-form symmetric 3x3 eigenvalues (all lanes, same wave time)
    {
        const float qd = (c00 + c11 + c22) * (1.0f / 3.0f);
        const float pp1 = c01 * c01 + c02 * c02 + c12 * c12;
        const float d00 = c00 - qd, d11 = c11 - qd, d22 = c22 - qd;
        const float p2 = d00 * d00 + d11 * d11 + d22 * d22 + 2.0f * pp1;
        float l1, l2, l3;
        if (p2 < 1e-30f) {
            l1 = l2 = l3 = qd;
        } else {
            const float p = sqrtf(p2 * (1.0f / 6.0f));
            const float inv = 1.0f / p;
            const float e00 = d00 * inv, e11 = d11 * inv, e22 = d22 * inv;
            const float e01 = c01 * inv, e02 = c02 * inv, e12 = c12 * inv;
            float detB = e00 * (e11 * e22 - e12 * e12)
                       - e01 * (e01 * e22 - e12 * e02)
                       + e02 * (e01 * e12 - e11 * e02);
            float r = 0.5f * detB;
            r = fminf(1.0f, fmaxf(-1.0f, r));
            const float phi = acosf(r) * (1.0f / 3.0f);
            l1 = qd + 2.0f * p * __cosf(phi);                          // largest
            l3 = qd + 2.0f * p * __cosf(phi + 2.0943951023931953f);    // smallest
            l2 = 3.0f * qd - l1 - l3;
        }
        if (s == 0) {
            fr[73] = (l1 - l2) / l1;
            fr[74] = (l2 - l3) / l1;
            fr[75] = l3 / l1;
        }
    }

    __syncthreads();   // weights + features visible

    // layer 1: features [subf*19, subf*19+19) x hidden [subh*16, subh*16+16)
    const int f0 = subf * 19;
    float h[16];
#pragma unroll
    for (int j = 0; j < 16; ++j) h[j] = (subf == 0) ? b1s[subh * 16 + j] : 0.0f;

#pragma unroll
    for (int ff = 0; ff < 19; ++ff) {
        const float v = fr[f0 + ff];
        const float4* w4 = reinterpret_cast<const float4*>(w1s + (f0 + ff) * 68 + subh * 16);
#pragma unroll
        for (int j4 = 0; j4 < 4; ++j4) {
            const float4 wv = w4[j4];
            h[4 * j4 + 0] = fmaf(v, wv.x, h[4 * j4 + 0]);
            h[4 * j4 + 1] = fmaf(v, wv.y, h[4 * j4 + 1]);
            h[4 * j4 + 2] = fmaf(v, wv.z, h[4 * j4 + 2]);
            h[4 * j4 + 3] = fmaf(v, wv.w, h[4 * j4 + 3]);
        }
    }

    // combine feature quarters (lane bits 0-1 = subf)
#pragma unroll
    for (int j = 0; j < 16; ++j) {
        h[j] += __shfl_xor(h[j], 1, 64);
        h[j] += __shfl_xor(h[j], 2, 64);
    }

    // layer 2: this thread handles j in [subf*4, subf*4+4) of its h[16]
    float o0 = 0.f, o1 = 0.f, o2 = 0.f;
#pragma unroll
    for (int jj = 0; jj < 4; ++jj) {
        const int j = subf * 4 + jj;
        const float r = fmaxf(h[j], 0.0f);
        const int hidx = subh * 16 + j;
        o0 = fmaf(r, w2s[hidx * 3 + 0], o0);
        o1 = fmaf(r, w2s[hidx * 3 + 1], o1);
        o2 = fmaf(r, w2s[hidx * 3 + 2], o2);
    }
    // combine across the full 16-lane group
#pragma unroll
    for (int off = 1; off < 16; off <<= 1) {
        o0 += __shfl_xor(o0, off, 64);
        o1 += __shfl_xor(o1, off, 64);
        o2 += __shfl_xor(o2, off, 64);
    }

    if (s == 0) {
        float* op = out + (size_t)gid * 3;
        op[0] = fmaxf(o0 + b2s[0], 0.0f);
        op[1] = fmaxf(o1 + b2s[1], 0.0f);
        op[2] = fmaxf(o2 + b2s[2], 0.0f);
    }
}

extern "C" void kernel_launch(void* const* d_in, const int* in_sizes, int n_in,
                              void* d_out, int out_size, void* d_ws, size_t ws_size,
                              hipStream_t stream) {
    const float* cloud = (const float*)d_in[0];   // [4,8192,3]
    const float* W1    = (const float*)d_in[1];   // [76,64]
    const float* b1    = (const float*)d_in[2];   // [64]
    const float* W2    = (const float*)d_in[3];   // [64,3]
    const float* b2    = (const float*)d_in[4];   // [3]
    float* out = (float*)d_out;                   // [4,8192,3]

    float4* pts4 = (float4*)d_ws;                                          // 512 KB
    unsigned short* knn = (unsigned short*)((char*)d_ws + 4 * NPTS * 16);  // 640 KB

    prep_kernel<<<dim3(128), dim3(256), 0, stream>>>(cloud, pts4);
    knn_kernel<<<dim3(512), dim3(1024), 0, stream>>>(pts4, knn);
    feat_mlp_kernel<<<dim3(1024), dim3(512), 0, stream>>>(pts4, W1, b1, W2, b2, knn, out);
}

// Round 14
// 174.767 us; speedup vs baseline: 1.0843x; 1.0843x over previous
//
#include <hip/hip_runtime.h>
#include <math.h>

#define KNN    10
#define NPTS   8192
#define HID    64
#define NF     76
#define Q      16                // queries per wave
#define CAP    64                // pass-2 collection capacity per query
#define F32_INF __uint_as_float(0x7F800000u)

__device__ __forceinline__ float rl(float v, int lane) {
    return __int_as_float(__builtin_amdgcn_readlane(__float_as_int(v), lane));
}

// ---------------------------------------------------------------------------
// Prep: pts4[i] = (x, y, z, x^2+y^2+z^2)  (w chain identical to all rounds).
// ---------------------------------------------------------------------------
__global__ __launch_bounds__(256) void prep_kernel(const float* __restrict__ cloud,
                                                   float4* __restrict__ pts4) {
    const int i = blockIdx.x * 256 + threadIdx.x;      // 0..32767
    const float x = cloud[i * 3 + 0];
    const float y = cloud[i * 3 + 1];
    const float z = cloud[i * 3 + 2];
    pts4[i] = make_float4(x, y, z, fmaf(z, z, fmaf(y, y, x * x)));
}

// ---------------------------------------------------------------------------
// KNN — R12 core (validated: absmax 4.39e-3) with HALVED barrier scope:
// block 512 thr = 8 waves = 2 query-groups x 4 candidate-quarters; grid 1024.
// Each barrier now syncs 8 waves (was 16); phase-3 serialization per block
// halves. Per-query chunk structure unchanged (64 chunk minima, rank-11
// threshold + 1e-3), keys bitwise-identical to R12 => selection unchanged.
// ---------------------------------------------------------------------------
__global__ __launch_bounds__(512) void knn_kernel(const float4* __restrict__ pts4,
                                                  unsigned short* __restrict__ knn_idx) {
    __shared__ unsigned long long coll[CAP][33];   // [slot][block query+pad], 16.9 KB
    __shared__ float pk[8][Q][17];                 // chunk minima, 8.7 KB
    __shared__ float tau_s[32];
    __shared__ int   cnt[32];

    const int t    = threadIdx.x;
    const int w    = t >> 6;                  // wave 0..7
    const int lane = t & 63;
    const int g    = w >> 2;                  // query group 0..1
    const int h    = w & 3;                   // candidate quarter 0..3
    const int bx   = blockIdx.x;              // 0..1023
    const int b    = bx >> 8;                 // batch
    const int n_base = (bx & 255) * 32 + g * Q;   // batch-local first query of group
    const int lq_base = g * Q;                // block-local query base
    const int cb0 = h * (NPTS / 4);           // candidate base for this wave

    const float4* pb = pts4 + b * NPTS;

    if (t < 32) cnt[t] = 0;                   // visible after barrier 1

    float qxs[Q], qys[Q], qzs[Q], qss[Q];
#pragma unroll
    for (int qq = 0; qq < Q; ++qq) {
        const float4 qv = pb[n_base + qq];
        qxs[qq] = qv.x; qys[qq] = qv.y; qzs[qq] = qv.z; qss[qq] = qv.w;
    }

    // ---------------- pass 1: per-lane minima over this quarter ----------------
    float vmin[Q];
#pragma unroll
    for (int qq = 0; qq < Q; ++qq) vmin[qq] = F32_INF;

    float4 cp = pb[cb0 + lane];               // coalesced vector load
    for (int ti = 0; ti < NPTS / 4 / 64; ++ti) {  // 32 tiles
        const float4 np = (ti < NPTS / 4 / 64 - 1) ? pb[cb0 + (ti + 1) * 64 + lane] : cp;
        const float a2x = -2.0f * cp.x;       // once per tile, amortized /16
        const float a2y = -2.0f * cp.y;
        const float a2z = -2.0f * cp.z;
        const float aw  = cp.w;
#pragma unroll
        for (int qq = 0; qq < Q; ++qq) {
            const float v = fmaf(a2x, qxs[qq], fmaf(a2y, qys[qq], fmaf(a2z, qzs[qq], aw)));
            vmin[qq] = fminf(vmin[qq], v);    // self included (rank arg handles it)
        }
        cp = np;
    }

#pragma unroll
    for (int qq = 0; qq < Q; ++qq) {
        float v = vmin[qq];
        v = fminf(v, __shfl_xor(v, 32, 64));
        v = fminf(v, __shfl_xor(v, 16, 64));
        if (lane < 16) pk[w][qq][lane] = v;
    }
    __syncthreads();                          // barrier 1: pk + cnt visible

    // h==0 waves (w = g*4): 11th smallest of 64 chunk minima -> tau for group
    if (h == 0) {
        float md[KNN + 1];
#pragma unroll
        for (int s = 0; s <= KNN; ++s) md[s] = F32_INF;
        const int qsel = lane & 15;           // 4-way replicated
#pragma unroll
        for (int cc = 0; cc < 64; ++cc) {
            float d = pk[g * 4 + (cc >> 4)][qsel][cc & 15];
#pragma unroll
            for (int u = 0; u <= KNN; ++u) {
                const float lo = fminf(md[u], d);
                d = fmaxf(md[u], d);
                md[u] = lo;
            }
        }
        if (lane < 16) tau_s[lq_base + lane] = md[KNN] + 1e-3f;
    }
    __syncthreads();                          // barrier 2: tau visible

    float taum[Q];
    {
        const float tv = tau_s[lq_base + (lane & 15)];
#pragma unroll
        for (int qq = 0; qq < Q; ++qq) taum[qq] = rl(tv, qq);   // -> SGPRs
    }

    // ---------------- pass 2: collect hits incl. self (rare) ----------------
    float4 cp2 = pb[cb0 + lane];
    int jcur = cb0 + lane;
    for (int ti = 0; ti < NPTS / 4 / 64; ++ti) {
        const float4 np = (ti < NPTS / 4 / 64 - 1) ? pb[cb0 + (ti + 1) * 64 + lane] : cp2;
        const float a2x = -2.0f * cp2.x;
        const float a2y = -2.0f * cp2.y;
        const float a2z = -2.0f * cp2.z;
        const float aw  = cp2.w;
#pragma unroll
        for (int qq = 0; qq < Q; ++qq) {
            const float v = fmaf(a2x, qxs[qq], fmaf(a2y, qys[qq], fmaf(a2z, qzs[qq], aw)));
            if (__builtin_expect(v <= taum[qq], 0)) {
                const float px = -0.5f * a2x;
                const float py = -0.5f * a2y;
                const float pz = -0.5f * a2z;
                const float dot = fmaf(pz, qzs[qq], fmaf(py, qys[qq], px * qxs[qq]));
                const float d2 = fmaf(-2.0f, dot, qss[qq] + aw);
                const unsigned int fb = __float_as_uint(d2);
                const unsigned int m =
                    fb ^ ((unsigned int)((int)fb >> 31) | 0x80000000u);  // monotone
                const unsigned long long key =
                    ((unsigned long long)m << 13) | (unsigned long long)(unsigned)jcur;
                const int slot = atomicAdd(&cnt[lq_base + qq], 1);
                if (slot < CAP) coll[slot][lq_base + qq] = key;
            }
        }
        cp2 = np; jcur += 64;
    }
    __syncthreads();

    // ---------------- phase 3: top-11 bubble, filter self by index ----------
    if (t < 32) {
        const int m = cnt[t];
        int mc = m;
#pragma unroll
        for (int off = 1; off < 32; off <<= 1)        // 32 active lanes only
            mc = max(mc, __shfl_xor(mc, off, 64));
        mc = __builtin_amdgcn_readfirstlane(mc);

        const int n = (bx & 255) * 32 + t;    // this lane's batch-local query

        unsigned long long md[KNN + 1];
#pragma unroll
        for (int s = 0; s <= KNN; ++s) md[s] = ~0ULL;

        if (mc <= CAP) {
            for (int cc = 0; cc < mc; ++cc) {
                unsigned long long key = (cc < m) ? coll[cc][t] : ~0ULL;
#pragma unroll
                for (int u = 0; u <= KNN; ++u) {
                    const bool lt = key < md[u];
                    const unsigned long long lo = lt ? key : md[u];
                    key = lt ? md[u] : key;
                    md[u] = lo;
                }
            }
        } else {
            const float4 qv = pb[n];
            for (int j = 0; j < NPTS; ++j) {
                const float4 p = pb[j];
                const float dot = fmaf(p.z, qv.z, fmaf(p.y, qv.y, p.x * qv.x));
                const float d2 = fmaf(-2.0f, dot, qv.w + p.w);
                const unsigned int fb = __float_as_uint(d2);
                const unsigned int mm =
                    fb ^ ((unsigned int)((int)fb >> 31) | 0x80000000u);
                unsigned long long key =
                    ((unsigned long long)mm << 13) | (unsigned long long)j;
                key = (j == n) ? ~0ULL : key;
#pragma unroll
                for (int u = 0; u <= KNN; ++u) {
                    const bool lt = key < md[u];
                    const unsigned long long lo = lt ? key : md[u];
                    key = lt ? md[u] : key;
                    md[u] = lo;
                }
            }
        }

        unsigned short* outp = knn_idx + ((size_t)b * NPTS + n) * KNN;
        int outc = 0;
#pragma unroll
        for (int u = 0; u <= KNN; ++u) {
            const int idx = (int)(md[u] & 8191u);
            if (outc < KNN && idx != n) outp[outc++] = (unsigned short)idx;
        }
    }
}

// ---------------------------------------------------------------------------
// Features + MLP — reverted to the R12 version (best measured). 4 threads
// per point (subh x subf 2x2), fp32 eigen, 256-thr blocks, grid 512.
// R13's 16-thr/point variant regressed: w1s b128 reads/point are layout-
// invariant (19) and the added shuffles bill the same DS pipe.
// ---------------------------------------------------------------------------
__global__ __launch_bounds__(256) void feat_mlp_kernel(const float4* __restrict__ pts4,
                                                       const float* __restrict__ W1,
                                                       const float* __restrict__ b1,
                                                       const float* __restrict__ W2,
                                                       const float* __restrict__ b2,
                                                       const unsigned short* __restrict__ knn_idx,
                                                       float* __restrict__ out) {
    __shared__ float w1s[NF * 68];            // padded stride
    __shared__ float b1s[HID];
    __shared__ float w2s[HID * 3];
    __shared__ float b2s[3];
    __shared__ float fs[64][NF + 1];          // stride 77

    const int t = threadIdx.x;
    for (int idx = t; idx < NF * HID; idx += 256)
        w1s[(idx >> 6) * 68 + (idx & 63)] = W1[idx];
    if (t < HID) b1s[t] = b1[t];
    if (t < HID * 3) w2s[t] = W2[t];
    if (t < 3) b2s[t] = b2[t];

    const int pl   = t >> 2;                  // point slot 0..63
    const int subh = t & 1;                   // hidden half
    const int subf = (t >> 1) & 1;            // feature half
    const int gid = blockIdx.x * 64 + pl;     // 0..32767
    const int b = gid >> 13;
    const int n = gid & (NPTS - 1);
    const float4* pb = pts4 + b * NPTS;

    if ((t & 3) == 0) {                       // one lane per quad builds
        const float4 cq = pb[n];
        const float cx = cq.x, cy = cq.y, cz = cq.z;

        float nx[KNN], ny[KNN], nz[KNN];
        const unsigned short* ki = knn_idx + (size_t)gid * KNN;
#pragma unroll
        for (int k = 0; k < KNN; ++k) {
            const int j = ki[k];
            const float4 p = pb[j];
            nx[k] = p.x; ny[k] = p.y; nz[k] = p.z;
        }

        float* fr = fs[pl];
        fr[0] = cx; fr[1] = cy; fr[2] = cz;
#pragma unroll
        for (int k = 0; k < KNN; ++k) {
            fr[3 + 3 * k + 0] = nx[k];
            fr[3 + 3 * k + 1] = ny[k];
            fr[3 + 3 * k + 2] = nz[k];
        }
#pragma unroll
        for (int k = 0; k < KNN; ++k) {
            fr[33 + 3 * k + 0] = nx[k] - cx;
            fr[33 + 3 * k + 1] = ny[k] - cy;
            fr[33 + 3 * k + 2] = nz[k] - cz;
        }
#pragma unroll
        for (int k = 0; k < KNN; ++k) {
            const float rx = nx[k] - cx, ry = ny[k] - cy, rz = nz[k] - cz;
            fr[63 + k] = sqrtf(fmaf(rz, rz, fmaf(ry, ry, rx * rx)));
        }

        float mx = 0.f, my = 0.f, mz = 0.f;
#pragma unroll
        for (int k = 0; k < KNN; ++k) { mx += nx[k]; my += ny[k]; mz += nz[k]; }
        mx *= (1.0f / KNN); my *= (1.0f / KNN); mz *= (1.0f / KNN);
        float c00 = 0.f, c01 = 0.f, c02 = 0.f, c11 = 0.f, c12 = 0.f, c22 = 0.f;
#pragma unroll
        for (int k = 0; k < KNN; ++k) {
            const float ex = nx[k] - mx, ey = ny[k] - my, ez = nz[k] - mz;
            c00 = fmaf(ex, ex, c00); c01 = fmaf(ex, ey, c01); c02 = fmaf(ex, ez, c02);
            c11 = fmaf(ey, ey, c11); c12 = fmaf(ey, ez, c12); c22 = fmaf(ez, ez, c22);
        }
        const float sc = 1.0f / (KNN - 1);
        c00 *= sc; c01 *= sc; c02 *= sc; c11 *= sc; c12 *= sc; c22 *= sc;

        // fp32 closed-form symmetric 3x3 eigenvalues
        const float qd = (c00 + c11 + c22) * (1.0f / 3.0f);
        const float pp1 = c01 * c01 + c02 * c02 + c12 * c12;
        const float d00 = c00 - qd, d11 = c11 - qd, d22 = c22 - qd;
        const float p2 = d00 * d00 + d11 * d11 + d22 * d22 + 2.0f * pp1;
        float l1, l2, l3;
        if (p2 < 1e-30f) {
            l1 = l2 = l3 = qd;
        } else {
            const float p = sqrtf(p2 * (1.0f / 6.0f));
            const float inv = 1.0f / p;
            const float e00 = d00 * inv, e11 = d11 * inv, e22 = d22 * inv;
            const float e01 = c01 * inv, e02 = c02 * inv, e12 = c12 * inv;
            float detB = e00 * (e11 * e22 - e12 * e12)
                       - e01 * (e01 * e22 - e12 * e02)
                       + e02 * (e01 * e12 - e11 * e02);
            float r = 0.5f * detB;
            r = fminf(1.0f, fmaxf(-1.0f, r));
            const float phi = acosf(r) * (1.0f / 3.0f);
            l1 = qd + 2.0f * p * __cosf(phi);                          // largest
            l3 = qd + 2.0f * p * __cosf(phi + 2.0943951023931953f);    // smallest
            l2 = 3.0f * qd - l1 - l3;
        }
        fr[73] = (l1 - l2) / l1;
        fr[74] = (l2 - l3) / l1;
        fr[75] = l3 / l1;
    }

    __syncthreads();   // weights + features visible

    const float* fr = fs[pl];
    const int f0 = subf * 38;

    float h[32];
#pragma unroll
    for (int j = 0; j < 32; ++j) h[j] = (subf == 0) ? b1s[subh * 32 + j] : 0.0f;

#pragma unroll 2
    for (int ff = 0; ff < 38; ++ff) {
        const int f = f0 + ff;
        const float v = fr[f];
        const float4* w4 = reinterpret_cast<const float4*>(w1s + f * 68 + subh * 32);
#pragma unroll
        for (int j4 = 0; j4 < 8; ++j4) {
            const float4 w = w4[j4];
            h[4 * j4 + 0] = fmaf(v, w.x, h[4 * j4 + 0]);
            h[4 * j4 + 1] = fmaf(v, w.y, h[4 * j4 + 1]);
            h[4 * j4 + 2] = fmaf(v, w.z, h[4 * j4 + 2]);
            h[4 * j4 + 3] = fmaf(v, w.w, h[4 * j4 + 3]);
        }
    }

    // combine feature halves (lanes differing in bit 1)
#pragma unroll
    for (int j = 0; j < 32; ++j) h[j] += __shfl_xor(h[j], 2, 64);

    float o0 = 0.f, o1 = 0.f, o2 = 0.f;
#pragma unroll
    for (int j = 0; j < 32; ++j) {
        const float r = fmaxf(h[j], 0.0f);
        const int jj = subh * 32 + j;
        o0 = fmaf(r, w2s[jj * 3 + 0], o0);
        o1 = fmaf(r, w2s[jj * 3 + 1], o1);
        o2 = fmaf(r, w2s[jj * 3 + 2], o2);
    }
    // combine hidden halves (lanes differing in bit 0)
    o0 += __shfl_xor(o0, 1, 64);
    o1 += __shfl_xor(o1, 1, 64);
    o2 += __shfl_xor(o2, 1, 64);

    if ((t & 3) == 0) {
        float* op = out + (size_t)gid * 3;
        op[0] = fmaxf(o0 + b2s[0], 0.0f);
        op[1] = fmaxf(o1 + b2s[1], 0.0f);
        op[2] = fmaxf(o2 + b2s[2], 0.0f);
    }
}

extern "C" void kernel_launch(void* const* d_in, const int* in_sizes, int n_in,
                              void* d_out, int out_size, void* d_ws, size_t ws_size,
                              hipStream_t stream) {
    const float* cloud = (const float*)d_in[0];   // [4,8192,3]
    const float* W1    = (const float*)d_in[1];   // [76,64]
    const float* b1    = (const float*)d_in[2];   // [64]
    const float* W2    = (const float*)d_in[3];   // [64,3]
    const float* b2    = (const float*)d_in[4];   // [3]
    float* out = (float*)d_out;                   // [4,8192,3]

    float4* pts4 = (float4*)d_ws;                                          // 512 KB
    unsigned short* knn = (unsigned short*)((char*)d_ws + 4 * NPTS * 16);  // 640 KB

    prep_kernel<<<dim3(128), dim3(256), 0, stream>>>(cloud, pts4);
    knn_kernel<<<dim3(1024), dim3(512), 0, stream>>>(pts4, knn);
    feat_mlp_kernel<<<dim3(512), dim3(256), 0, stream>>>(pts4, W1, b1, W2, b2, knn, out);
}